// Round 17
// baseline (35.579 us; speedup 1.0000x reference)
//
#include <hip/hip_runtime.h>
#include <math.h>

// MotionBlur: out = p0*Vtop + p1*Vbot + p3*Hleft + p2*Hright (8-tap box sums).
// x: [64,1,512,512] f32; logits,gumbel: [1,4] f32; out: [64,1,512,512] f32.
//
// Fully-hoisted streaming wave (R15 structure) with waves/EU PINNED to 4,4:
// amdgpu_waves_per_eu(4,4) makes the allocator target exactly 128 VGPR
// (R16 showed launch_bounds' min-only semantics let it squeeze to 64 and
// spill). ~117 VGPR needed -> fits -> 4 waves/SIMD, 16 waves/CU, 8192 waves
// = 2.0 residency generations. All loads in the preamble, zero in the loop.

#define IMG   512
#define IMG4  128   // float4s per row

static __device__ __forceinline__ float4 f4z() {
    return make_float4(0.f, 0.f, 0.f, 0.f);
}

__global__
__attribute__((amdgpu_flat_work_group_size(64, 64)))
__attribute__((amdgpu_waves_per_eu(4, 4)))
void motion_blur_kernel(
    const float* __restrict__ x,
    const float* __restrict__ logits,
    const float* __restrict__ gnoise,
    float* __restrict__ out)
{
    const int lane = threadIdx.x & 63;

    // XCD-chunk swizzle: 8192 blocks, 8 XCDs -> 1024 contiguous logical per
    // XCD (= 8 whole images per XCD).
    const int bid  = blockIdx.x;
    const int lbid = (bid & 7) * 1024 + (bid >> 3);

    const int img  = lbid >> 7;        // 128 blocks per image
    const int rem  = lbid & 127;
    const int ct   = rem >> 6;         // column tile 0/1 (256 cols each)
    const int y0   = (rem & 63) * 8;   // 8-row band
    const int c4t  = ct * 64;          // tile base in float4 units
    const int c4   = c4t + lane;       // this lane's float4 column block

    const float4* __restrict__ xi4 =
        reinterpret_cast<const float4*>(x) + (size_t)img * (IMG * IMG4);

    // ---- batched halo load: lanes 0..31 cover 8 rows x 4 halo blocks ----
    // l&3: 0 -> block c4t-2, 1 -> c4t-1, 2 -> c4t+64, 3 -> c4t+65; row y0+(l>>2)
    const int hb   = lane & 3;
    const int hc4  = c4t + ((hb < 2) ? (hb - 2) : (62 + hb));
    const int hrow = y0 + (lane >> 2);
    float4 hq = f4z();
    if (lane < 32 && (unsigned)hc4 < (unsigned)IMG4)
        hq = xi4[hrow * IMG4 + hc4];

    // ---- band rows y0-7 .. y0+15 -> v[0..22], all issued back-to-back ----
    float4 v[23];
    #pragma unroll
    for (int k = 0; k < 23; ++k) {
        const int r = y0 - 7 + k;
        float4 t = f4z();
        if ((unsigned)r < (unsigned)IMG) t = xi4[r * IMG4 + c4];
        v[k] = t;
    }

    // gumbel-softmax probs (tau=1): softmax(logits + noise)
    float l0 = logits[0] + gnoise[0];
    float l1 = logits[1] + gnoise[1];
    float l2 = logits[2] + gnoise[2];
    float l3 = logits[3] + gnoise[3];
    float mx = fmaxf(fmaxf(l0, l1), fmaxf(l2, l3));
    float e0 = expf(l0 - mx), e1 = expf(l1 - mx);
    float e2 = expf(l2 - mx), e3 = expf(l3 - mx);
    float inv = 1.0f / (e0 + e1 + e2 + e3);
    const float p0  = e0 * inv;   // north: rows y-7..y
    const float p1  = e1 * inv;   // south: rows y+1..y+8
    const float p2  = e2 * inv;   // east:  cols x+1..x+8
    const float p3  = e3 * inv;   // west:  cols x-7..x
    const float q32 = p3 - p2;
    const float np3 = -p3;

    // halo prefix (once per wave; meaningful on lanes 0..31)
    const float hP0 = hq.x;
    const float hP1 = hP0 + hq.y;
    const float hP2 = hP1 + hq.z;
    const float hP3 = hP2 + hq.w;

    // vertical box sums for first output row
    float4 VA = f4z(), VB = f4z();
    #pragma unroll
    for (int k = 0; k < 8; ++k) {       // rows y0-7..y0
        VA.x += v[k].x; VA.y += v[k].y; VA.z += v[k].z; VA.w += v[k].w;
    }
    #pragma unroll
    for (int k = 8; k < 16; ++k) {      // rows y0+1..y0+8
        VB.x += v[k].x; VB.y += v[k].y; VB.z += v[k].z; VB.w += v[k].w;
    }

    const int lm2 = (lane - 2) & 63;
    const int lm1 = (lane - 1) & 63;
    const int lp1 = (lane + 1) & 63;
    const int lp2 = (lane + 2) & 63;
    // halo redistribution source (only meaningful on lanes 0,1,62,63)
    const int hbase = (lane < 2) ? lane : (lane - 60);

    float* __restrict__ obase =
        out + (size_t)img * (IMG * IMG) + (size_t)y0 * IMG + 4 * c4;

    #pragma unroll
    for (int i = 0; i < 8; ++i) {
        const float4 cur = v[7 + i];
        // intra-block inclusive prefix
        const float L0 = cur.x;
        const float L1 = L0 + cur.y;
        const float L2 = L1 + cur.z;
        const float L3 = L2 + cur.w;

        // neighbor-block prefixes
        float Lm0 = __shfl(L0, lm2), Lm1 = __shfl(L1, lm2),
              Lm2_ = __shfl(L2, lm2), Lm3 = __shfl(L3, lm2);
        float Lp0 = __shfl(L0, lp2), Lp1 = __shfl(L1, lp2),
              Lp2_ = __shfl(L2, lp2), Lp3 = __shfl(L3, lp2);

        // halo values for this row, pulled from the batched-halo lanes
        const int hsrc = 4 * i + hbase;
        const float hV0 = __shfl(hP0, hsrc);
        const float hV1 = __shfl(hP1, hsrc);
        const float hV2 = __shfl(hP2, hsrc);
        const float hV3 = __shfl(hP3, hsrc);
        if (lane < 2)   { Lm0 = hV0; Lm1 = hV1; Lm2_ = hV2; Lm3 = hV3; }
        if (lane >= 62) { Lp0 = hV0; Lp1 = hV1; Lp2_ = hV2; Lp3 = hV3; }

        // block sums of x-1 / x+1
        float sm1 = __shfl(L3, lm1);
        const float sm1h = __shfl(hP3, 4 * i + 1);   // block -1, this row
        if (lane == 0) sm1 = sm1h;
        float sp1 = __shfl(L3, lp1);
        const float sp1h = __shfl(hP3, 4 * i + 2);   // block +64, this row
        if (lane == 63) sp1 = sp1h;

        // W_j = (Lm3 + sm1) + L_j - Lm_j ; E_j = (L3 + sp1) + Lp_j - L_j
        const float base = p3 * (Lm3 + sm1) + p2 * (L3 + sp1);
        float4 r4;
        r4.x = fmaf(p0, VA.x, fmaf(p1, VB.x,
                 fmaf(q32, L0, fmaf(np3, Lm0, fmaf(p2, Lp0, base)))));
        r4.y = fmaf(p0, VA.y, fmaf(p1, VB.y,
                 fmaf(q32, L1, fmaf(np3, Lm1, fmaf(p2, Lp1, base)))));
        r4.z = fmaf(p0, VA.z, fmaf(p1, VB.z,
                 fmaf(q32, L2, fmaf(np3, Lm2_, fmaf(p2, Lp2_, base)))));
        r4.w = fmaf(p0, VA.w, fmaf(p1, VB.w,
                 fmaf(q32, L3, fmaf(np3, Lm3, fmaf(p2, Lp3, base)))));
        *reinterpret_cast<float4*>(obase + (size_t)i * IMG) = r4;

        if (i < 7) {
            // step vertical window: VA gains row y0+1+i, loses y0-7+i;
            // VB gains row y0+9+i, loses y0+1+i.
            const float4 a = v[8 + i];
            const float4 b = v[i];
            const float4 n = v[16 + i];
            VA.x += a.x - b.x; VA.y += a.y - b.y;
            VA.z += a.z - b.z; VA.w += a.w - b.w;
            VB.x += n.x - a.x; VB.y += n.y - a.y;
            VB.z += n.z - a.z; VB.w += n.w - a.w;
        }
    }
}

extern "C" void kernel_launch(void* const* d_in, const int* in_sizes, int n_in,
                              void* d_out, int out_size, void* d_ws, size_t ws_size,
                              hipStream_t stream) {
    const float* x      = (const float*)d_in[0];
    const float* logits = (const float*)d_in[1];
    const float* gn     = (const float*)d_in[2];
    float* outp         = (float*)d_out;
    // 64 images x 2 column tiles x 64 row-bands = 8192 single-wave blocks
    motion_blur_kernel<<<dim3(8192), dim3(64), 0, stream>>>(x, logits, gn, outp);
}

// Round 18
// 28.961 us; speedup vs baseline: 1.2285x; 1.2285x over previous
//
#include <hip/hip_runtime.h>
#include <math.h>

// MotionBlur: out = p0*Vtop + p1*Vbot + p3*Hleft + p2*Hright (8-tap box sums).
// x: [64,1,512,512] f32; logits,gumbel: [1,4] f32; out: [64,1,512,512] f32.
//
// Fully-hoisted streaming wave, 16-row bands: rows y0-7..y0+23 in flat v[31]
// (124 VGPR, static indices), ONE full-wave batched halo load (lane l ->
// halo block {-2,-1,+64,+65}[l>>4], row y0+(l&15)), zero loads in the loop.
// Read amplification 31/16 = 1.94x (was 23/8 = 2.9x) -> per-CU L1 volume
// drops 33%, which is the measured wall (MSHR x HBM-RT, L3 cold each
// dispatch). __launch_bounds__(64,3): the only budget the backend honors
// without squeezing to 64 VGPR + spilling (R14/R16/R17 evidence).

#define IMG   512
#define IMG4  128   // float4s per row
#define BH    16    // output rows per wave

static __device__ __forceinline__ float4 f4z() {
    return make_float4(0.f, 0.f, 0.f, 0.f);
}

__global__ __launch_bounds__(64, 3) void motion_blur_kernel(
    const float* __restrict__ x,
    const float* __restrict__ logits,
    const float* __restrict__ gnoise,
    float* __restrict__ out)
{
    const int lane = threadIdx.x & 63;

    // XCD-chunk swizzle: 4096 blocks, 8 XCDs -> 512 contiguous logical per XCD
    const int bid  = blockIdx.x;
    const int lbid = (bid & 7) * 512 + (bid >> 3);

    const int img  = lbid >> 6;        // 64 blocks per image
    const int rem  = lbid & 63;
    const int ct   = rem >> 5;         // column tile 0/1 (256 cols each)
    const int y0   = (rem & 31) * BH;  // 16-row band
    const int c4t  = ct * 64;          // tile base in float4 units
    const int c4   = c4t + lane;       // this lane's float4 column block

    const float4* __restrict__ xi4 =
        reinterpret_cast<const float4*>(x) + (size_t)img * (IMG * IMG4);

    // ---- batched halo load: 64 lanes = 16 rows x 4 halo blocks ----
    // sel = lane>>4: 0 -> block c4t-2, 1 -> c4t-1, 2 -> c4t+64, 3 -> c4t+65
    // row = y0 + (lane & 15)
    const int sel  = lane >> 4;
    const int hc4  = c4t + ((sel < 2) ? (sel - 2) : (62 + sel));
    const int hrow = y0 + (lane & 15);
    float4 hq = f4z();
    if ((unsigned)hc4 < (unsigned)IMG4)
        hq = xi4[hrow * IMG4 + hc4];

    // ---- band rows y0-7 .. y0+23 -> v[0..30], all issued back-to-back ----
    float4 v[31];
    #pragma unroll
    for (int k = 0; k < 31; ++k) {
        const int r = y0 - 7 + k;
        float4 t = f4z();
        if ((unsigned)r < (unsigned)IMG) t = xi4[r * IMG4 + c4];
        v[k] = t;
    }

    // gumbel-softmax probs (tau=1): softmax(logits + noise)
    float l0 = logits[0] + gnoise[0];
    float l1 = logits[1] + gnoise[1];
    float l2 = logits[2] + gnoise[2];
    float l3 = logits[3] + gnoise[3];
    float mx = fmaxf(fmaxf(l0, l1), fmaxf(l2, l3));
    float e0 = expf(l0 - mx), e1 = expf(l1 - mx);
    float e2 = expf(l2 - mx), e3 = expf(l3 - mx);
    float inv = 1.0f / (e0 + e1 + e2 + e3);
    const float p0  = e0 * inv;   // north: rows y-7..y
    const float p1  = e1 * inv;   // south: rows y+1..y+8
    const float p2  = e2 * inv;   // east:  cols x+1..x+8
    const float p3  = e3 * inv;   // west:  cols x-7..x
    const float q32 = p3 - p2;
    const float np3 = -p3;

    // halo prefix (per lane, one halo block each)
    const float hP0 = hq.x;
    const float hP1 = hP0 + hq.y;
    const float hP2 = hP1 + hq.z;
    const float hP3 = hP2 + hq.w;

    // vertical box sums for first output row
    float4 VA = f4z(), VB = f4z();
    #pragma unroll
    for (int k = 0; k < 8; ++k) {       // rows y0-7..y0
        VA.x += v[k].x; VA.y += v[k].y; VA.z += v[k].z; VA.w += v[k].w;
    }
    #pragma unroll
    for (int k = 8; k < 16; ++k) {      // rows y0+1..y0+8
        VB.x += v[k].x; VB.y += v[k].y; VB.z += v[k].z; VB.w += v[k].w;
    }

    const int lm2 = (lane - 2) & 63;
    const int lm1 = (lane - 1) & 63;
    const int lp1 = (lane + 1) & 63;
    const int lp2 = (lane + 2) & 63;
    // halo redistribution base lane (meaningful on lanes 0,1,62,63):
    // lane0 -> halo sel0 (block -2) lanes 0..15; lane1 -> sel1 lanes 16..31;
    // lane62 -> sel2 (block +64) lanes 32..47; lane63 -> sel3 lanes 48..63.
    const int hbase = ((lane < 2) ? lane : (lane - 60)) << 4;

    float* __restrict__ obase =
        out + (size_t)img * (IMG * IMG) + (size_t)y0 * IMG + 4 * c4;

    #pragma unroll
    for (int i = 0; i < BH; ++i) {
        const float4 cur = v[7 + i];
        // intra-block inclusive prefix
        const float L0 = cur.x;
        const float L1 = L0 + cur.y;
        const float L2 = L1 + cur.z;
        const float L3 = L2 + cur.w;

        // neighbor-block prefixes
        float Lm0 = __shfl(L0, lm2), Lm1 = __shfl(L1, lm2),
              Lm2_ = __shfl(L2, lm2), Lm3 = __shfl(L3, lm2);
        float Lp0 = __shfl(L0, lp2), Lp1 = __shfl(L1, lp2),
              Lp2_ = __shfl(L2, lp2), Lp3 = __shfl(L3, lp2);

        // halo values for this row, pulled from the batched-halo lanes
        const int hsrc = hbase + i;
        const float hV0 = __shfl(hP0, hsrc);
        const float hV1 = __shfl(hP1, hsrc);
        const float hV2 = __shfl(hP2, hsrc);
        const float hV3 = __shfl(hP3, hsrc);
        if (lane < 2)   { Lm0 = hV0; Lm1 = hV1; Lm2_ = hV2; Lm3 = hV3; }
        if (lane >= 62) { Lp0 = hV0; Lp1 = hV1; Lp2_ = hV2; Lp3 = hV3; }

        // block sums of x-1 / x+1
        float sm1 = __shfl(L3, lm1);
        const float sm1h = __shfl(hP3, 16 + i);   // block -1, this row
        if (lane == 0) sm1 = sm1h;
        float sp1 = __shfl(L3, lp1);
        const float sp1h = __shfl(hP3, 32 + i);   // block +64, this row
        if (lane == 63) sp1 = sp1h;

        // W_j = (Lm3 + sm1) + L_j - Lm_j ; E_j = (L3 + sp1) + Lp_j - L_j
        const float base = p3 * (Lm3 + sm1) + p2 * (L3 + sp1);
        float4 r4;
        r4.x = fmaf(p0, VA.x, fmaf(p1, VB.x,
                 fmaf(q32, L0, fmaf(np3, Lm0, fmaf(p2, Lp0, base)))));
        r4.y = fmaf(p0, VA.y, fmaf(p1, VB.y,
                 fmaf(q32, L1, fmaf(np3, Lm1, fmaf(p2, Lp1, base)))));
        r4.z = fmaf(p0, VA.z, fmaf(p1, VB.z,
                 fmaf(q32, L2, fmaf(np3, Lm2_, fmaf(p2, Lp2_, base)))));
        r4.w = fmaf(p0, VA.w, fmaf(p1, VB.w,
                 fmaf(q32, L3, fmaf(np3, Lm3, fmaf(p2, Lp3, base)))));
        *reinterpret_cast<float4*>(obase + (size_t)i * IMG) = r4;

        if (i < BH - 1) {
            // step vertical window: VA gains row y0+1+i, loses y0-7+i;
            // VB gains row y0+9+i, loses y0+1+i.
            const float4 a = v[8 + i];
            const float4 b = v[i];
            const float4 n = v[16 + i];
            VA.x += a.x - b.x; VA.y += a.y - b.y;
            VA.z += a.z - b.z; VA.w += a.w - b.w;
            VB.x += n.x - a.x; VB.y += n.y - a.y;
            VB.z += n.z - a.z; VB.w += n.w - a.w;
        }
    }
}

extern "C" void kernel_launch(void* const* d_in, const int* in_sizes, int n_in,
                              void* d_out, int out_size, void* d_ws, size_t ws_size,
                              hipStream_t stream) {
    const float* x      = (const float*)d_in[0];
    const float* logits = (const float*)d_in[1];
    const float* gn     = (const float*)d_in[2];
    float* outp         = (float*)d_out;
    // 64 images x 2 column tiles x 32 row-bands (16 rows) = 4096 single-wave blocks
    motion_blur_kernel<<<dim3(4096), dim3(64), 0, stream>>>(x, logits, gn, outp);
}